// Round 4
// baseline (482.325 us; speedup 1.0000x reference)
//
#include <hip/hip_runtime.h>
#include <hip/hip_bf16.h>
#include <hip/hip_fp16.h>

#define NN   10000
#define FIN  512
#define FOUT 256
#define NPAD 10240
#define LRA  0.2f

typedef __attribute__((ext_vector_type(4))) float    f32x4;
typedef __attribute__((ext_vector_type(4))) int      i32x4;
typedef __attribute__((ext_vector_type(8))) _Float16 f16x8;
typedef __attribute__((ext_vector_type(8))) short    bf16x8;

static __device__ __forceinline__ short f2bf(float x) {
  unsigned u = __builtin_bit_cast(unsigned, x);
  u += 0x7fffu + ((u >> 16) & 1u);   // RNE; x always finite here
  return (short)(u >> 16);
}
static __device__ __forceinline__ float bf2f(short s) {
  unsigned u = ((unsigned)(unsigned short)s) << 16;
  return __builtin_bit_cast(float, u);
}

// ---------------- K0: Wt[c][k] = f16(W[k][c]) ----------------
__global__ __launch_bounds__(256) void k0_wt(const float* __restrict__ W,
                                             _Float16* __restrict__ Wt) {
  int idx = blockIdx.x * 256 + threadIdx.x;
  int k = idx >> 8, c = idx & 255;
  Wt[(size_t)c * FIN + k] = (_Float16)W[(size_t)k * FOUT + c];
}

// ---------------- K1: Wh = h @ W (f16 MFMA, fp32 accum) ----------------
__global__ __launch_bounds__(256) void k1_wh(const float* __restrict__ h,
                                             const _Float16* __restrict__ Wt,
                                             float* __restrict__ Wh) {
  const int r0 = blockIdx.x * 64;
  const int t = threadIdx.x;
  const int w = t >> 6, l = t & 63;
  const int lr = l & 15, lq = l >> 4;
  f32x4 acc[4][4];
#pragma unroll
  for (int m = 0; m < 4; ++m)
#pragma unroll
    for (int n = 0; n < 4; ++n)
#pragma unroll
      for (int q = 0; q < 4; ++q) acc[m][n][q] = 0.f;

  for (int kk = 0; kk < FIN; kk += 32) {
    f16x8 af[4];
#pragma unroll
    for (int m = 0; m < 4; ++m) {
      int gr = r0 + m * 16 + lr;
      if (gr < NN) {
        const f32x4* p = (const f32x4*)(h + (size_t)gr * FIN + kk + lq * 8);
        f32x4 v0 = p[0], v1 = p[1];
#pragma unroll
        for (int i = 0; i < 4; ++i) { af[m][i] = (_Float16)v0[i]; af[m][i + 4] = (_Float16)v1[i]; }
      } else {
#pragma unroll
        for (int i = 0; i < 8; ++i) af[m][i] = (_Float16)0.f;
      }
    }
#pragma unroll
    for (int n = 0; n < 4; ++n) {
      int gc = w * 64 + n * 16 + lr;
      f16x8 bf = *(const f16x8*)(Wt + (size_t)gc * FIN + kk + lq * 8);
#pragma unroll
      for (int m = 0; m < 4; ++m)
        acc[m][n] = __builtin_amdgcn_mfma_f32_16x16x32_f16(af[m], bf, acc[m][n], 0, 0, 0);
    }
  }
#pragma unroll
  for (int m = 0; m < 4; ++m)
#pragma unroll
    for (int n = 0; n < 4; ++n)
#pragma unroll
      for (int q = 0; q < 4; ++q) {
        int gr = r0 + m * 16 + lq * 4 + q;
        if (gr < NN) Wh[(size_t)gr * FOUT + w * 64 + n * 16 + lr] = acc[m][n][q];
      }
}

// ---------------- K2: e1/e2 (padded) + WhT[c][r] bf16 ----------------
__global__ __launch_bounds__(256) void k2_et(const float* __restrict__ Wh,
                                             const float* __restrict__ a,
                                             float* __restrict__ e1,
                                             float* __restrict__ e2,
                                             short* __restrict__ WhT) {
  __shared__ float tile[64][65];
  const int r0 = blockIdx.x * 64;
  const int t = threadIdx.x;
  {
    int r = r0 + (t >> 2);
    int sub = t & 3;
    float s1 = 0.f, s2 = 0.f;
    if (r < NN) {
      for (int i = 0; i < 64; ++i) {
        int c = sub + 4 * i;
        float v = Wh[(size_t)r * FOUT + c];
        s1 += v * a[c];
        s2 += v * a[FOUT + c];
      }
    }
    s1 += __shfl_xor(s1, 1); s1 += __shfl_xor(s1, 2);
    s2 += __shfl_xor(s2, 1); s2 += __shfl_xor(s2, 2);
    if (sub == 0) {
      e1[r] = (r < NN) ? s1 : 0.f;
      e2[r] = (r < NN) ? s2 : 0.f;
    }
  }
  for (int c0 = 0; c0 < FOUT; c0 += 64) {
    __syncthreads();
#pragma unroll
    for (int i = 0; i < 16; ++i) {
      int e = t + 256 * i;
      int row = e >> 6, col = e & 63;
      int grd = r0 + row;
      tile[row][col] = (grd < NN) ? Wh[(size_t)grd * FOUT + c0 + col] : 0.f;
    }
    __syncthreads();
#pragma unroll
    for (int i = 0; i < 16; ++i) {
      int e = t + 256 * i;
      int c = e >> 6, rr = e & 63;
      WhT[(size_t)(c0 + c) * NPAD + r0 + rr] = f2bf(tile[rr][c]);
    }
  }
}

// ---------------- KP: bit-pack adj (400 MB -> 12.8 MB) ----------------
__global__ __launch_bounds__(256) void kp_bits(const int* __restrict__ adj,
                                               unsigned long long* __restrict__ bits) {
  const int lane = threadIdx.x & 63;
  const int wid = (blockIdx.x * 256 + threadIdx.x) >> 6;
  const int nw = (gridDim.x * 256) >> 6;
  const int TOT = NPAD * (NPAD / 64);   // 1,638,400
  for (int it = wid; it < TOT; it += nw) {
    int row = it / (NPAD / 64);
    int w = it - row * (NPAD / 64);
    int j = w * 64 + lane;
    int v = 0;
    if (row < NN && j < NN) v = adj[(size_t)row * NN + j];
    unsigned long long m = __ballot(v > 0);
    if (lane == 0) bits[it] = m;
  }
}

// ---------------- K3: partial masked-softmax @ Wh ----------------
#define K3_PHASE(PH, BREG, BUF)                                               \
  {                                                                           \
    const int jg_ = jbase + (PH) * 64;                                        \
    bf16x8 bv[2][2];                                                          \
    {                                                                         \
      const short* bp_ = WhT + jg_ + lq * 8;                                  \
      _Pragma("unroll")                                                       \
      for (int kt = 0; kt < 2; ++kt) {                                        \
        bv[kt][0] = *(const bf16x8*)(bp_ + bcol0 + kt * 32);                  \
        bv[kt][1] = *(const bf16x8*)(bp_ + bcol1 + kt * 32);                  \
      }                                                                       \
    }                                                                         \
    {                                                                         \
      const int jl_ = (PH) * 64 + sub * 32;                                   \
      f32x4 ev[8];                                                            \
      _Pragma("unroll")                                                       \
      for (int q = 0; q < 8; ++q) ev[q] = *(const f32x4*)(e2s + jl_ + q * 4); \
      bf16x8 pf[4];                                                           \
      _Pragma("unroll")                                                       \
      for (int i = 0; i < 32; ++i) {                                          \
        float x = e1v + ev[i >> 2][i & 3];                                    \
        float s = fmaxf(x, LRA * x);                                          \
        float p = ((BREG) >> i) & 1 ? __expf(s) : 0.f;                        \
        rs += p;                                                              \
        pf[i >> 3][i & 7] = f2bf(p);                                          \
      }                                                                       \
      char* wb_ = (BUF) + prow * 128;                                         \
      _Pragma("unroll")                                                       \
      for (int c = 0; c < 4; ++c)                                             \
        *(bf16x8*)(wb_ + ((sub * 64 + c * 16) ^ psw)) = pf[c];                \
    }                                                                         \
    __syncthreads();                                                          \
    _Pragma("unroll")                                                         \
    for (int kt = 0; kt < 2; ++kt) {                                          \
      const int ao_ = (kt * 64 + lq * 16) ^ axor;                             \
      _Pragma("unroll")                                                       \
      for (int m = 0; m < 16; ++m) {                                          \
        bf16x8 av = *(const bf16x8*)((BUF) + m * 2048 + lr * 128 + ao_);      \
        acc[m][0] = __builtin_amdgcn_mfma_f32_16x16x32_bf16(av, bv[kt][0], acc[m][0], 0, 0, 0); \
        acc[m][1] = __builtin_amdgcn_mfma_f32_16x16x32_bf16(av, bv[kt][1], acc[m][1], 0, 0, 0); \
      }                                                                       \
    }                                                                         \
  }

__global__ __launch_bounds__(512, 2) void k3_part(const unsigned int* __restrict__ bits32,
                                                  const float* __restrict__ e1,
                                                  const float* __restrict__ e2,
                                                  const short* __restrict__ WhT,
                                                  short* __restrict__ pnum,
                                                  float* __restrict__ pden,
                                                  int nslice) {
  __shared__ __align__(16) char Plds[2][32768];
  __shared__ float e2s[1280];
  const int jlen = NPAD / nslice;
  const int s = blockIdx.x % nslice;
  const int rowblk = blockIdx.x / nslice;
  const int jbase = s * jlen;
  const int r0 = rowblk * 256;
  const int t = threadIdx.x;
  const int w = t >> 6, l = t & 63;
  const int lr = l & 15, lq = l >> 4;
  const int prow = t >> 1, sub = t & 1;
  const int psw = (prow & 7) << 4;
  const int axor = (lr & 7) << 4;
  const int growp = r0 + prow;
  const float e1v = e1[growp];
  const size_t bcol0 = (size_t)(w * 32 + lr) * NPAD;
  const size_t bcol1 = bcol0 + (size_t)16 * NPAD;
  const unsigned int* brow = bits32 + (size_t)growp * (NPAD / 32) + (jbase >> 5) + sub;

  for (int i = t; i < jlen / 4; i += 512)
    ((f32x4*)e2s)[i] = ((const f32x4*)(e2 + jbase))[i];

  f32x4 acc[16][2];
#pragma unroll
  for (int m = 0; m < 16; ++m)
#pragma unroll
    for (int n = 0; n < 2; ++n)
#pragma unroll
      for (int q = 0; q < 4; ++q) acc[m][n][q] = 0.f;
  float rs = 0.f;

  unsigned int bA = brow[0];
  unsigned int bB = brow[2];
  __syncthreads();

  const int nph = jlen >> 6;
  for (int ph = 0; ph < nph; ph += 2) {
    unsigned int bA2 = (ph + 2 < nph) ? brow[(ph + 2) * 2] : 0u;
    unsigned int bB2 = (ph + 3 < nph) ? brow[(ph + 3) * 2] : 0u;
    K3_PHASE(ph,     bA, &Plds[0][0]);
    K3_PHASE(ph + 1, bB, &Plds[1][0]);
    bA = bA2; bB = bB2;
  }

  rs += __shfl_xor(rs, 1);
  if (sub == 0) pden[(size_t)s * NPAD + growp] = rs;
#pragma unroll
  for (int m = 0; m < 16; ++m)
#pragma unroll
    for (int n = 0; n < 2; ++n)
#pragma unroll
      for (int q = 0; q < 4; ++q) {
        int row = m * 16 + lq * 4 + q;
        pnum[((size_t)s * NPAD + r0 + row) * FOUT + w * 32 + n * 16 + lr] =
            f2bf(acc[m][n][q]);
      }
}

// ---------------- K4: reduce slices, normalize, elu ----------------
__global__ __launch_bounds__(256) void k4_out(const short* __restrict__ pnum,
                                              const float* __restrict__ pden,
                                              float* __restrict__ out,
                                              int nslice) {
  const int row = blockIdx.x;
  const int c = threadIdx.x;
  float den = 0.f;
  for (int s = 0; s < nslice; ++s) den += pden[(size_t)s * NPAD + row];
  float num = 0.f;
  for (int s = 0; s < nslice; ++s)
    num += bf2f(pnum[((size_t)s * NPAD + row) * FOUT + c]);
  float v = num / den;
  out[(size_t)row * FOUT + c] = (v > 0.f) ? v : (__expf(v) - 1.f);
}

// ---------------- Fallback (ws too small): R2 fused k3 ----------------
#define OLD_LOAD(J0N, AV, EV)                                               \
  {                                                                         \
    const int jn_ = (J0N) + jb;                                             \
    EV[0] = *(const f32x4*)(e2 + jn_);                                      \
    EV[1] = *(const f32x4*)(e2 + jn_ + 4);                                  \
    EV[2] = *(const f32x4*)(e2 + jn_ + 128);                                \
    EV[3] = *(const f32x4*)(e2 + jn_ + 132);                                \
    if (rowok && (J0N) + 256 <= NN) {                                       \
      AV[0] = *(const i32x4*)(adj + adjrow + jn_);                          \
      AV[1] = *(const i32x4*)(adj + adjrow + jn_ + 4);                      \
      AV[2] = *(const i32x4*)(adj + adjrow + jn_ + 128);                    \
      AV[3] = *(const i32x4*)(adj + adjrow + jn_ + 132);                    \
    } else {                                                                \
      _Pragma("unroll")                                                     \
      for (int p_ = 0; p_ < 4; ++p_) {                                      \
        _Pragma("unroll")                                                   \
        for (int i_ = 0; i_ < 4; ++i_) {                                    \
          int j_ = jn_ + (p_ >> 1) * 128 + (p_ & 1) * 4 + i_;               \
          AV[p_][i_] = (rowok && j_ < NN) ? adj[adjrow + j_] : 0;           \
        }                                                                   \
      }                                                                     \
    }                                                                       \
  }

#define OLD_PHASE(J0, AV, EV, BUF)                                          \
  {                                                                         \
    bf16x8 pf0, pf1;                                                        \
    _Pragma("unroll")                                                       \
    for (int i = 0; i < 8; ++i) {                                           \
      float x = e1v + EV[i >> 2][i & 3];                                    \
      float s = fmaxf(x, LRA * x);                                          \
      float p = (AV[i >> 2][i & 3] > 0) ? __expf(s) : 0.f;                  \
      rs += p; pf0[i] = f2bf(p);                                            \
    }                                                                       \
    _Pragma("unroll")                                                       \
    for (int i = 0; i < 8; ++i) {                                           \
      float x = e1v + EV[2 + (i >> 2)][i & 3];                              \
      float s = fmaxf(x, LRA * x);                                          \
      float p = (AV[2 + (i >> 2)][i & 3] > 0) ? __expf(s) : 0.f;            \
      rs += p; pf1[i] = f2bf(p);                                            \
    }                                                                       \
    {                                                                       \
      char* wb_ = (BUF) + prow * 512;                                       \
      const int sw_ = (prow & 7) << 4;                                      \
      *(bf16x8*)(wb_ + ((psub * 16) ^ sw_)) = pf0;                          \
      *(bf16x8*)(wb_ + ((256 + psub * 16) ^ sw_)) = pf1;                    \
    }                                                                       \
    __syncthreads();                                                        \
    _Pragma("unroll")                                                       \
    for (int kt = 0; kt < 8; ++kt) {                                        \
      const int boff_ = (kt * 64 + lq * 16) ^ ((lr & 7) << 4);              \
      bf16x8 a0 = *(const bf16x8*)((BUF) + lr * 512 + boff_);               \
      bf16x8 a1 = *(const bf16x8*)((BUF) + (16 + lr) * 512 + boff_);        \
      const short* bp_ = WhT + (J0) + kt * 32 + lq * 8;                     \
      bf16x8 b0 = *(const bf16x8*)(bp_ + bcol0);                            \
      bf16x8 b1 = *(const bf16x8*)(bp_ + bcol1);                            \
      acc[0][0] = __builtin_amdgcn_mfma_f32_16x16x32_bf16(a0, b0, acc[0][0], 0, 0, 0); \
      acc[1][0] = __builtin_amdgcn_mfma_f32_16x16x32_bf16(a1, b0, acc[1][0], 0, 0, 0); \
      acc[0][1] = __builtin_amdgcn_mfma_f32_16x16x32_bf16(a0, b1, acc[0][1], 0, 0, 0); \
      acc[1][1] = __builtin_amdgcn_mfma_f32_16x16x32_bf16(a1, b1, acc[1][1], 0, 0, 0); \
    }                                                                       \
  }

__global__ __launch_bounds__(512) void k3_old(const int* __restrict__ adj,
                                              const float* __restrict__ e1,
                                              const float* __restrict__ e2,
                                              const short* __restrict__ WhT,
                                              float* __restrict__ out) {
  __shared__ __align__(16) char Plds[2][32 * 512];
  __shared__ float rowsum[32];
  const int r0 = blockIdx.x * 32;
  const int t = threadIdx.x;
  const int w = t >> 6, l = t & 63;
  const int lr = l & 15, lq = l >> 4;
  const int prow = t >> 4;
  const int psub = t & 15;
  const int jb = psub * 8;
  const int gr = r0 + prow;
  const bool rowok = (gr < NN);
  const float e1v = rowok ? e1[gr] : 0.f;
  const size_t adjrow = (size_t)gr * NN;
  const size_t bcol0 = (size_t)(w * 32 + lr) * NPAD;
  const size_t bcol1 = (size_t)(w * 32 + 16 + lr) * NPAD;
  float rs = 0.f;
  f32x4 acc[2][2];
#pragma unroll
  for (int m = 0; m < 2; ++m)
#pragma unroll
    for (int n = 0; n < 2; ++n)
#pragma unroll
      for (int q = 0; q < 4; ++q) acc[m][n][q] = 0.f;

  const int NT = (NN + 255) / 256;
  i32x4 avA[4], avB[4];
  f32x4 evA[4], evB[4];
  OLD_LOAD(0, avA, evA);
  for (int jt = 0; jt < NT; jt += 2) {
    OLD_LOAD((jt + 1) * 256, avB, evB);
    OLD_PHASE(jt * 256, avA, evA, &Plds[0][0]);
    if (jt + 2 < NT) OLD_LOAD((jt + 2) * 256, avA, evA);
    OLD_PHASE((jt + 1) * 256, avB, evB, &Plds[1][0]);
  }
  rs += __shfl_xor(rs, 1); rs += __shfl_xor(rs, 2);
  rs += __shfl_xor(rs, 4); rs += __shfl_xor(rs, 8);
  if (psub == 0) rowsum[prow] = rs;
  __syncthreads();
#pragma unroll
  for (int m = 0; m < 2; ++m)
#pragma unroll
    for (int n = 0; n < 2; ++n)
#pragma unroll
      for (int q = 0; q < 4; ++q) {
        int row = m * 16 + lq * 4 + q;
        int grow = r0 + row;
        if (grow < NN) {
          float v = acc[m][n][q] / rowsum[row];
          float o = (v > 0.f) ? v : (__expf(v) - 1.f);
          out[(size_t)grow * FOUT + w * 32 + n * 16 + lr] = o;
        }
      }
}

extern "C" void kernel_launch(void* const* d_in, const int* in_sizes, int n_in,
                              void* d_out, int out_size, void* d_ws, size_t ws_size,
                              hipStream_t stream) {
  const float* h   = (const float*)d_in[0];
  const int*   adj = (const int*)d_in[1];
  const float* W   = (const float*)d_in[2];
  const float* a   = (const float*)d_in[3];
  float* out = (float*)d_out;
  char* ws = (char*)d_ws;
  _Float16* Wt  = (_Float16*)(ws + 0);            // 262144
  float*    Wh  = (float*)(ws + 262144);          // -> 10502144
  short*    WhT = (short*)(ws + 10502144);        // -> 15745024
  float*    e1  = (float*)(ws + 15745024);        // -> 15785984
  float*    e2  = (float*)(ws + 15785984);        // -> 15826944
  unsigned long long* bits = (unsigned long long*)(ws + 15826944);  // -> 28934144
  (void)in_sizes; (void)n_in; (void)out_size;

  int nslice = 0;
  if (ws_size >= (size_t)113475584) nslice = 16;
  else if (ws_size >= (size_t)71204864) nslice = 8;

  k0_wt<<<dim3(512), dim3(256), 0, stream>>>(W, Wt);
  k1_wh<<<dim3(157), dim3(256), 0, stream>>>(h, Wt, Wh);
  k2_et<<<dim3(160), dim3(256), 0, stream>>>(Wh, a, e1, e2, WhT);

  if (nslice) {
    float* pden = (float*)(ws + 28934144);
    short* pnum = (short*)(ws + 28934144 + (size_t)nslice * NPAD * 4);
    kp_bits<<<dim3(2048), dim3(256), 0, stream>>>(adj, bits);
    k3_part<<<dim3(40 * nslice), dim3(512), 0, stream>>>(
        (const unsigned int*)bits, e1, e2, WhT, pnum, pden, nslice);
    // ---- ATTRIBUTION PROBE: duplicate k3_part into scratch (R4 only).
    // dur_us delta vs R3 == t(k3_part). Outputs unused by k4; deterministic.
    size_t probe_base = 28934144 + (size_t)nslice * NPAD * 4 + (size_t)nslice * NPAD * FOUT * 2;
    if (nslice == 16 && ws_size >= probe_base + (size_t)nslice * NPAD * 4 + (size_t)nslice * NPAD * FOUT * 2) {
      float* pden2 = (float*)(ws + probe_base);
      short* pnum2 = (short*)(ws + probe_base + (size_t)nslice * NPAD * 4);
      k3_part<<<dim3(40 * nslice), dim3(512), 0, stream>>>(
          (const unsigned int*)bits, e1, e2, WhT, pnum2, pden2, nslice);
    }
    k4_out<<<dim3(NN), dim3(256), 0, stream>>>(pnum, pden, out, nslice);
  } else {
    k3_old<<<dim3(313), dim3(512), 0, stream>>>(adj, e1, e2, WhT, out);
  }
}

// Round 5
// 368.151 us; speedup vs baseline: 1.3101x; 1.3101x over previous
//
#include <hip/hip_runtime.h>
#include <hip/hip_bf16.h>
#include <hip/hip_fp16.h>

#define NN    10000
#define FIN   512
#define FOUT  256
#define NPAD  10240
#define LRA   0.2f
#define NSL   20          // slices; JLEN multiple of 256 (bit-chunk aligned)
#define JLEN  512         // NPAD / NSL
#define NPH   8           // JLEN / 64
#define WPR   160         // 64-bit words per row = NPAD/64

typedef __attribute__((ext_vector_type(4))) float    f32x4;
typedef __attribute__((ext_vector_type(4))) int      i32x4;
typedef __attribute__((ext_vector_type(8))) _Float16 f16x8;
typedef __attribute__((ext_vector_type(8))) short    bf16x8;
typedef __attribute__((ext_vector_type(2))) unsigned long long u64x2;

static __device__ __forceinline__ short f2bf(float x) {
  unsigned u = __builtin_bit_cast(unsigned, x);
  u += 0x7fffu + ((u >> 16) & 1u);   // RNE; x always finite here
  return (short)(u >> 16);
}
static __device__ __forceinline__ float bf2f(short s) {
  unsigned u = ((unsigned)(unsigned short)s) << 16;
  return __builtin_bit_cast(float, u);
}

// ---------------- K0: Wt[c][k] = f16(W[k][c]) ----------------
__global__ __launch_bounds__(256) void k0_wt(const float* __restrict__ W,
                                             _Float16* __restrict__ Wt) {
  int idx = blockIdx.x * 256 + threadIdx.x;
  int k = idx >> 8, c = idx & 255;
  Wt[(size_t)c * FIN + k] = (_Float16)W[(size_t)k * FOUT + c];
}

// ---------------- K1: Wh = h @ W (f16 MFMA, fp32 accum) ----------------
__global__ __launch_bounds__(256) void k1_wh(const float* __restrict__ h,
                                             const _Float16* __restrict__ Wt,
                                             float* __restrict__ Wh) {
  const int r0 = blockIdx.x * 64;
  const int t = threadIdx.x;
  const int w = t >> 6, l = t & 63;
  const int lr = l & 15, lq = l >> 4;
  f32x4 acc[4][4];
#pragma unroll
  for (int m = 0; m < 4; ++m)
#pragma unroll
    for (int n = 0; n < 4; ++n)
#pragma unroll
      for (int q = 0; q < 4; ++q) acc[m][n][q] = 0.f;

  for (int kk = 0; kk < FIN; kk += 32) {
    f16x8 af[4];
#pragma unroll
    for (int m = 0; m < 4; ++m) {
      int gr = r0 + m * 16 + lr;
      if (gr < NN) {
        const f32x4* p = (const f32x4*)(h + (size_t)gr * FIN + kk + lq * 8);
        f32x4 v0 = p[0], v1 = p[1];
#pragma unroll
        for (int i = 0; i < 4; ++i) { af[m][i] = (_Float16)v0[i]; af[m][i + 4] = (_Float16)v1[i]; }
      } else {
#pragma unroll
        for (int i = 0; i < 8; ++i) af[m][i] = (_Float16)0.f;
      }
    }
#pragma unroll
    for (int n = 0; n < 4; ++n) {
      int gc = w * 64 + n * 16 + lr;
      f16x8 bf = *(const f16x8*)(Wt + (size_t)gc * FIN + kk + lq * 8);
#pragma unroll
      for (int m = 0; m < 4; ++m)
        acc[m][n] = __builtin_amdgcn_mfma_f32_16x16x32_f16(af[m], bf, acc[m][n], 0, 0, 0);
    }
  }
#pragma unroll
  for (int m = 0; m < 4; ++m)
#pragma unroll
    for (int n = 0; n < 4; ++n)
#pragma unroll
      for (int q = 0; q < 4; ++q) {
        int gr = r0 + m * 16 + lq * 4 + q;
        if (gr < NN) Wh[(size_t)gr * FOUT + w * 64 + n * 16 + lr] = acc[m][n][q];
      }
}

// ---------------- K2: e1/e2 (padded) + WhT[c][r] bf16 ----------------
__global__ __launch_bounds__(256) void k2_et(const float* __restrict__ Wh,
                                             const float* __restrict__ a,
                                             float* __restrict__ e1,
                                             float* __restrict__ e2,
                                             short* __restrict__ WhT) {
  __shared__ float tile[64][65];
  const int r0 = blockIdx.x * 64;
  const int t = threadIdx.x;
  {
    int r = r0 + (t >> 2);
    int sub = t & 3;
    float s1 = 0.f, s2 = 0.f;
    if (r < NN) {
      for (int i = 0; i < 64; ++i) {
        int c = sub + 4 * i;
        float v = Wh[(size_t)r * FOUT + c];
        s1 += v * a[c];
        s2 += v * a[FOUT + c];
      }
    }
    s1 += __shfl_xor(s1, 1); s1 += __shfl_xor(s1, 2);
    s2 += __shfl_xor(s2, 1); s2 += __shfl_xor(s2, 2);
    if (sub == 0) {
      e1[r] = (r < NN) ? s1 : 0.f;
      e2[r] = (r < NN) ? s2 : 0.f;
    }
  }
  for (int c0 = 0; c0 < FOUT; c0 += 64) {
    __syncthreads();
#pragma unroll
    for (int i = 0; i < 16; ++i) {
      int e = t + 256 * i;
      int row = e >> 6, col = e & 63;
      int grd = r0 + row;
      tile[row][col] = (grd < NN) ? Wh[(size_t)grd * FOUT + c0 + col] : 0.f;
    }
    __syncthreads();
#pragma unroll
    for (int i = 0; i < 16; ++i) {
      int e = t + 256 * i;
      int c = e >> 6, rr = e & 63;
      WhT[(size_t)(c0 + c) * NPAD + r0 + rr] = f2bf(tile[rr][c]);
    }
  }
}

// ---------------- KP: bit-pack adj, vectorized (16 B/lane) ----------------
// One wave per row. Chunk = 256 j. Word (chunk*4+c), bit k  <->  j = chunk*256 + 4k + c.
__global__ __launch_bounds__(256) void kp_bits(const int* __restrict__ adj,
                                               unsigned long long* __restrict__ bits) {
  const int lane = threadIdx.x & 63;
  const int row = (blockIdx.x * 256 + threadIdx.x) >> 6;   // 0..NPAD-1
  unsigned long long* orow = bits + (size_t)row * WPR;
  if (row >= NN) {
    for (int c = lane; c < WPR; c += 64) orow[c] = 0ULL;
    return;
  }
  const int* arow = adj + (size_t)row * NN;
  const int j4 = lane * 4;
  i32x4 cur = *(const i32x4*)(arow + j4);                  // chunk 0 (full)
  for (int c = 0; c < 40; ++c) {
    i32x4 nxt;
    if (c < 38) {
      nxt = *(const i32x4*)(arow + (c + 1) * 256 + j4);
    } else if (c == 38) {                                  // chunk 39 is partial
      int jb = 39 * 256 + j4;
#pragma unroll
      for (int q = 0; q < 4; ++q) nxt[q] = (jb + q < NN) ? arow[jb + q] : 0;
    } else {
      nxt[0] = nxt[1] = nxt[2] = nxt[3] = 0;
    }
    unsigned long long b0 = __ballot(cur[0] > 0);
    unsigned long long b1 = __ballot(cur[1] > 0);
    unsigned long long b2 = __ballot(cur[2] > 0);
    unsigned long long b3 = __ballot(cur[3] > 0);
    if (lane < 4) {
      unsigned long long v = (lane == 0) ? b0 : (lane == 1) ? b1 : (lane == 2) ? b2 : b3;
      orow[c * 4 + lane] = v;
    }
    cur = nxt;
  }
}

// ---------------- K3: partial masked-softmax @ Wh ----------------
// Block = 256 rows x 512-j slice. 1024 thr = 16 waves, 4M x 4N (wave: 64 rows x 64 cols).
// acc[4][4] = 64 VGPR -> 4 waves/SIMD. P double-buffered, software-pipelined:
// produce P(ph+1) before MFMA(ph); one barrier per phase; setprio around MFMA.
#define PRODUCE(PH, BUF)                                                      \
  {                                                                           \
    const int jl_ = (PH) * 64 + sub * 16;                                     \
    f32x4 ea = *(const f32x4*)(e2s + jl_);                                    \
    f32x4 eb = *(const f32x4*)(e2s + jl_ + 4);                                \
    f32x4 ec = *(const f32x4*)(e2s + jl_ + 8);                                \
    f32x4 ed = *(const f32x4*)(e2s + jl_ + 12);                               \
    const unsigned int m16 = mk[(PH) >> 1] >> (((PH) & 1) * 16);              \
    bf16x8 pf0, pf1;                                                          \
    _Pragma("unroll")                                                         \
    for (int i = 0; i < 16; ++i) {                                            \
      float x = e1v + ((i < 4) ? ea[i & 3] : (i < 8) ? eb[i & 3]              \
                       : (i < 12) ? ec[i & 3] : ed[i & 3]);                   \
      float sv = fmaxf(x, LRA * x);                                           \
      float p = ((m16 >> (((i & 3) * 4) + (i >> 2))) & 1) ? __expf(sv) : 0.f; \
      rs += p;                                                                \
      if (i < 8) pf0[i] = f2bf(p); else pf1[i & 7] = f2bf(p);                 \
    }                                                                         \
    char* wb_ = (BUF) + prow * 128;                                           \
    *(bf16x8*)(wb_ + ((sub * 32) ^ psw)) = pf0;                               \
    *(bf16x8*)(wb_ + ((sub * 32 + 16) ^ psw)) = pf1;                          \
  }

#define CONSUME(PH, BUF)                                                      \
  {                                                                           \
    const short* bp_ = bbase + (PH) * 64 + lq * 8;                            \
    __builtin_amdgcn_s_setprio(1);                                            \
    _Pragma("unroll")                                                         \
    for (int kt = 0; kt < 2; ++kt) {                                          \
      bf16x8 bv0 = *(const bf16x8*)(bp_ + bco0 + kt * 32);                    \
      bf16x8 bv1 = *(const bf16x8*)(bp_ + bco1 + kt * 32);                    \
      bf16x8 bv2 = *(const bf16x8*)(bp_ + bco2 + kt * 32);                    \
      bf16x8 bv3 = *(const bf16x8*)(bp_ + bco3 + kt * 32);                    \
      const int ao_ = (kt * 64 + lq * 16) ^ axor;                             \
      _Pragma("unroll")                                                       \
      for (int m = 0; m < 4; ++m) {                                           \
        bf16x8 av = *(const bf16x8*)((BUF) + (wm * 64 + m * 16 + lr) * 128 + ao_); \
        acc[m][0] = __builtin_amdgcn_mfma_f32_16x16x32_bf16(av, bv0, acc[m][0], 0, 0, 0); \
        acc[m][1] = __builtin_amdgcn_mfma_f32_16x16x32_bf16(av, bv1, acc[m][1], 0, 0, 0); \
        acc[m][2] = __builtin_amdgcn_mfma_f32_16x16x32_bf16(av, bv2, acc[m][2], 0, 0, 0); \
        acc[m][3] = __builtin_amdgcn_mfma_f32_16x16x32_bf16(av, bv3, acc[m][3], 0, 0, 0); \
      }                                                                       \
    }                                                                         \
    __builtin_amdgcn_s_setprio(0);                                            \
  }

__global__ __launch_bounds__(1024) void k3_part(const unsigned long long* __restrict__ bits,
                                                const float* __restrict__ e1,
                                                const float* __restrict__ e2,
                                                const short* __restrict__ WhT,
                                                short* __restrict__ pnum,
                                                float* __restrict__ pden) {
  __shared__ __align__(16) char Plds[2][32768];   // [256 rows][64 j] bf16, XOR-swizzled
  __shared__ float e2s[JLEN];
  const int id = blockIdx.x;
  const int s = id % NSL;
  const int r0 = (id / NSL) * 256;
  const int jbase = s * JLEN;
  const int t = threadIdx.x;
  const int w = t >> 6, l = t & 63;
  const int lr = l & 15, lq = l >> 4;
  const int wm = w >> 2, wn = w & 3;
  const int prow = t >> 2, sub = t & 3;           // producer: 4 thr/row, 16 j each
  const int psw = (prow & 7) << 4;
  const int axor = (lr & 7) << 4;
  const int grow = r0 + prow;
  const float e1v = e1[grow];
  const short* bbase = WhT + jbase;
  const unsigned int bco0 = (unsigned)(wn * 64 + 0 * 16 + lr) * NPAD;
  const unsigned int bco1 = (unsigned)(wn * 64 + 1 * 16 + lr) * NPAD;
  const unsigned int bco2 = (unsigned)(wn * 64 + 2 * 16 + lr) * NPAD;
  const unsigned int bco3 = (unsigned)(wn * 64 + 3 * 16 + lr) * NPAD;

  if (t < JLEN / 4) ((f32x4*)e2s)[t] = ((const f32x4*)(e2 + jbase))[t];

  // precompute per-phase 16-bit masks from the packed adjacency
  unsigned int mk[NPH / 2];
  {
    const unsigned long long* wr = bits + (size_t)grow * WPR + (jbase >> 6);
    u64x2 wv0 = *(const u64x2*)(wr + 0);
    u64x2 wv1 = *(const u64x2*)(wr + 2);
    u64x2 wv2 = *(const u64x2*)(wr + 4);
    u64x2 wv3 = *(const u64x2*)(wr + 6);
    unsigned long long wd[8];
    wd[0] = wv0[0]; wd[1] = wv0[1]; wd[2] = wv1[0]; wd[3] = wv1[1];
    wd[4] = wv2[0]; wd[5] = wv2[1]; wd[6] = wv3[0]; wd[7] = wv3[1];
#pragma unroll
    for (int ph = 0; ph < NPH; ++ph) {
      const int base = (ph & 3) * 16 + sub * 4;
      const unsigned long long* wc = wd + (ph >> 2) * 4;
      unsigned int m16 = (unsigned int)((wc[0] >> base) & 0xFULL)
                       | ((unsigned int)((wc[1] >> base) & 0xFULL) << 4)
                       | ((unsigned int)((wc[2] >> base) & 0xFULL) << 8)
                       | ((unsigned int)((wc[3] >> base) & 0xFULL) << 12);
      if (ph & 1) mk[ph >> 1] |= m16 << 16; else mk[ph >> 1] = m16;
    }
  }

  f32x4 acc[4][4];
#pragma unroll
  for (int m = 0; m < 4; ++m)
#pragma unroll
    for (int n = 0; n < 4; ++n)
#pragma unroll
      for (int q = 0; q < 4; ++q) acc[m][n][q] = 0.f;
  float rs = 0.f;

  __syncthreads();                    // e2s ready
  PRODUCE(0, &Plds[0][0]);
#pragma unroll
  for (int ph = 0; ph < NPH; ++ph) {
    __syncthreads();                  // P(ph) visible; prev reads of buf[(ph+1)&1] done
    if (ph + 1 < NPH) PRODUCE(ph + 1, &Plds[(ph + 1) & 1][0]);
    CONSUME(ph, &Plds[ph & 1][0]);
  }

  rs += __shfl_xor(rs, 1); rs += __shfl_xor(rs, 2);
  if (sub == 0) pden[(size_t)s * NPAD + grow] = rs;
#pragma unroll
  for (int m = 0; m < 4; ++m)
#pragma unroll
    for (int n = 0; n < 4; ++n)
#pragma unroll
      for (int q = 0; q < 4; ++q) {
        int row = wm * 64 + m * 16 + lq * 4 + q;
        pnum[((size_t)s * NPAD + r0 + row) * FOUT + wn * 64 + n * 16 + lr] =
            f2bf(acc[m][n][q]);
      }
}

// ---------------- K4: reduce slices, normalize, elu ----------------
__global__ __launch_bounds__(256) void k4_out(const short* __restrict__ pnum,
                                              const float* __restrict__ pden,
                                              float* __restrict__ out) {
  const int row = blockIdx.x;
  const int c = threadIdx.x;
  float den = 0.f;
#pragma unroll
  for (int s = 0; s < NSL; ++s) den += pden[(size_t)s * NPAD + row];
  float num = 0.f;
#pragma unroll
  for (int s = 0; s < NSL; ++s) num += bf2f(pnum[((size_t)s * NPAD + row) * FOUT + c]);
  float v = num / den;
  out[(size_t)row * FOUT + c] = (v > 0.f) ? v : (__expf(v) - 1.f);
}

// ---------------- Fallback (ws too small): R2 fused k3 ----------------
#define OLD_LOAD(J0N, AV, EV)                                               \
  {                                                                         \
    const int jn_ = (J0N) + jb;                                             \
    EV[0] = *(const f32x4*)(e2 + jn_);                                      \
    EV[1] = *(const f32x4*)(e2 + jn_ + 4);                                  \
    EV[2] = *(const f32x4*)(e2 + jn_ + 128);                                \
    EV[3] = *(const f32x4*)(e2 + jn_ + 132);                                \
    if (rowok && (J0N) + 256 <= NN) {                                       \
      AV[0] = *(const i32x4*)(adj + adjrow + jn_);                          \
      AV[1] = *(const i32x4*)(adj + adjrow + jn_ + 4);                      \
      AV[2] = *(const i32x4*)(adj + adjrow + jn_ + 128);                    \
      AV[3] = *(const i32x4*)(adj + adjrow + jn_ + 132);                    \
    } else {                                                                \
      _Pragma("unroll")                                                     \
      for (int p_ = 0; p_ < 4; ++p_) {                                      \
        _Pragma("unroll")                                                   \
        for (int i_ = 0; i_ < 4; ++i_) {                                    \
          int j_ = jn_ + (p_ >> 1) * 128 + (p_ & 1) * 4 + i_;               \
          AV[p_][i_] = (rowok && j_ < NN) ? adj[adjrow + j_] : 0;           \
        }                                                                   \
      }                                                                     \
    }                                                                       \
  }

#define OLD_PHASE(J0, AV, EV, BUF)                                          \
  {                                                                         \
    bf16x8 pf0, pf1;                                                        \
    _Pragma("unroll")                                                       \
    for (int i = 0; i < 8; ++i) {                                           \
      float x = e1v + EV[i >> 2][i & 3];                                    \
      float s = fmaxf(x, LRA * x);                                          \
      float p = (AV[i >> 2][i & 3] > 0) ? __expf(s) : 0.f;                  \
      rs += p; pf0[i] = f2bf(p);                                            \
    }                                                                       \
    _Pragma("unroll")                                                       \
    for (int i = 0; i < 8; ++i) {                                           \
      float x = e1v + EV[2 + (i >> 2)][i & 3];                              \
      float s = fmaxf(x, LRA * x);                                          \
      float p = (AV[2 + (i >> 2)][i & 3] > 0) ? __expf(s) : 0.f;            \
      rs += p; pf1[i] = f2bf(p);                                            \
    }                                                                       \
    {                                                                       \
      char* wb_ = (BUF) + prow * 512;                                       \
      const int sw_ = (prow & 7) << 4;                                      \
      *(bf16x8*)(wb_ + ((psub * 16) ^ sw_)) = pf0;                          \
      *(bf16x8*)(wb_ + ((256 + psub * 16) ^ sw_)) = pf1;                    \
    }                                                                       \
    __syncthreads();                                                        \
    _Pragma("unroll")                                                       \
    for (int kt = 0; kt < 8; ++kt) {                                        \
      const int boff_ = (kt * 64 + lq * 16) ^ ((lr & 7) << 4);              \
      bf16x8 a0 = *(const bf16x8*)((BUF) + lr * 512 + boff_);               \
      bf16x8 a1 = *(const bf16x8*)((BUF) + (16 + lr) * 512 + boff_);        \
      const short* bp_ = WhT + (J0) + kt * 32 + lq * 8;                     \
      bf16x8 b0 = *(const bf16x8*)(bp_ + bcol0);                            \
      bf16x8 b1 = *(const bf16x8*)(bp_ + bcol1);                            \
      acc[0][0] = __builtin_amdgcn_mfma_f32_16x16x32_bf16(a0, b0, acc[0][0], 0, 0, 0); \
      acc[1][0] = __builtin_amdgcn_mfma_f32_16x16x32_bf16(a1, b0, acc[1][0], 0, 0, 0); \
      acc[0][1] = __builtin_amdgcn_mfma_f32_16x16x32_bf16(a0, b1, acc[0][1], 0, 0, 0); \
      acc[1][1] = __builtin_amdgcn_mfma_f32_16x16x32_bf16(a1, b1, acc[1][1], 0, 0, 0); \
    }                                                                       \
  }

__global__ __launch_bounds__(512) void k3_old(const int* __restrict__ adj,
                                              const float* __restrict__ e1,
                                              const float* __restrict__ e2,
                                              const short* __restrict__ WhT,
                                              float* __restrict__ out) {
  __shared__ __align__(16) char Plds[2][32 * 512];
  __shared__ float rowsum[32];
  const int r0 = blockIdx.x * 32;
  const int t = threadIdx.x;
  const int w = t >> 6, l = t & 63;
  const int lr = l & 15, lq = l >> 4;
  const int prow = t >> 4;
  const int psub = t & 15;
  const int jb = psub * 8;
  const int gr = r0 + prow;
  const bool rowok = (gr < NN);
  const float e1v = rowok ? e1[gr] : 0.f;
  const size_t adjrow = (size_t)gr * NN;
  const size_t bcol0 = (size_t)(w * 32 + lr) * NPAD;
  const size_t bcol1 = (size_t)(w * 32 + 16 + lr) * NPAD;
  float rs = 0.f;
  f32x4 acc[2][2];
#pragma unroll
  for (int m = 0; m < 2; ++m)
#pragma unroll
    for (int n = 0; n < 2; ++n)
#pragma unroll
      for (int q = 0; q < 4; ++q) acc[m][n][q] = 0.f;

  const int NT = (NN + 255) / 256;
  i32x4 avA[4], avB[4];
  f32x4 evA[4], evB[4];
  OLD_LOAD(0, avA, evA);
  for (int jt = 0; jt < NT; jt += 2) {
    OLD_LOAD((jt + 1) * 256, avB, evB);
    OLD_PHASE(jt * 256, avA, evA, &Plds[0][0]);
    if (jt + 2 < NT) OLD_LOAD((jt + 2) * 256, avA, evA);
    OLD_PHASE((jt + 1) * 256, avB, evB, &Plds[1][0]);
  }
  rs += __shfl_xor(rs, 1); rs += __shfl_xor(rs, 2);
  rs += __shfl_xor(rs, 4); rs += __shfl_xor(rs, 8);
  if (psub == 0) rowsum[prow] = rs;
  __syncthreads();
#pragma unroll
  for (int m = 0; m < 2; ++m)
#pragma unroll
    for (int n = 0; n < 2; ++n)
#pragma unroll
      for (int q = 0; q < 4; ++q) {
        int row = m * 16 + lq * 4 + q;
        int grow = r0 + row;
        if (grow < NN) {
          float v = acc[m][n][q] / rowsum[row];
          float o = (v > 0.f) ? v : (__expf(v) - 1.f);
          out[(size_t)grow * FOUT + w * 32 + n * 16 + lr] = o;
        }
      }
}

extern "C" void kernel_launch(void* const* d_in, const int* in_sizes, int n_in,
                              void* d_out, int out_size, void* d_ws, size_t ws_size,
                              hipStream_t stream) {
  const float* h   = (const float*)d_in[0];
  const int*   adj = (const int*)d_in[1];
  const float* W   = (const float*)d_in[2];
  const float* a   = (const float*)d_in[3];
  float* out = (float*)d_out;
  char* ws = (char*)d_ws;
  _Float16* Wt  = (_Float16*)(ws + 0);            // 262144
  float*    Wh  = (float*)(ws + 262144);          // -> 10502144
  short*    WhT = (short*)(ws + 10502144);        // -> 15745024
  float*    e1  = (float*)(ws + 15745024);        // -> 15785984
  float*    e2  = (float*)(ws + 15785984);        // -> 15826944
  unsigned long long* bits = (unsigned long long*)(ws + 15826944);  // 13107200 -> 28934144
  float*    pden = (float*)(ws + 28934144);       // 20*10240*4 = 819200 -> 29753344
  short*    pnum = (short*)(ws + 29753344);       // 20*10240*256*2 = 104857600 -> 134610944
  (void)in_sizes; (void)n_in; (void)out_size;

  const bool big = ws_size >= (size_t)134610944;

  k0_wt<<<dim3(512), dim3(256), 0, stream>>>(W, Wt);
  k1_wh<<<dim3(157), dim3(256), 0, stream>>>(h, Wt, Wh);
  k2_et<<<dim3(160), dim3(256), 0, stream>>>(Wh, a, e1, e2, WhT);

  if (big) {
    kp_bits<<<dim3(NPAD / 4), dim3(256), 0, stream>>>(adj, bits);
    k3_part<<<dim3((NPAD / 256) * NSL), dim3(1024), 0, stream>>>(
        bits, e1, e2, WhT, pnum, pden);
    k4_out<<<dim3(NN), dim3(256), 0, stream>>>(pnum, pden, out);
  } else {
    k3_old<<<dim3(313), dim3(512), 0, stream>>>(adj, e1, e2, WhT, out);
  }
}

// Round 6
// 314.803 us; speedup vs baseline: 1.5322x; 1.1695x over previous
//
#include <hip/hip_runtime.h>
#include <hip/hip_bf16.h>
#include <hip/hip_fp16.h>

#define NN    10000
#define FIN   512
#define FOUT  256
#define NPAD  10240
#define LRA   0.2f
#define NSL   20          // slices; jbase multiple of 256 (bit-chunk aligned)
#define JLEN  512         // NPAD / NSL
#define NPH   8           // JLEN / 64
#define WPR   160         // 64-bit words per row = NPAD/64

typedef __attribute__((ext_vector_type(4))) float    f32x4;
typedef __attribute__((ext_vector_type(4))) int      i32x4;
typedef __attribute__((ext_vector_type(8))) _Float16 f16x8;
typedef __attribute__((ext_vector_type(8))) short    bf16x8;
typedef __attribute__((ext_vector_type(2))) unsigned long long u64x2;

static __device__ __forceinline__ short f2bf(float x) {
  unsigned u = __builtin_bit_cast(unsigned, x);
  u += 0x7fffu + ((u >> 16) & 1u);   // RNE; x always finite here
  return (short)(u >> 16);
}
static __device__ __forceinline__ float bf2f(short s) {
  unsigned u = ((unsigned)(unsigned short)s) << 16;
  return __builtin_bit_cast(float, u);
}

// ---------------- K0: Wt[c][k] = f16(W[k][c]) ----------------
__global__ __launch_bounds__(256) void k0_wt(const float* __restrict__ W,
                                             _Float16* __restrict__ Wt) {
  int idx = blockIdx.x * 256 + threadIdx.x;
  int k = idx >> 8, c = idx & 255;
  Wt[(size_t)c * FIN + k] = (_Float16)W[(size_t)k * FOUT + c];
}

// ---------------- K1: Wh = h @ W (f16 MFMA, fp32 accum) ----------------
__global__ __launch_bounds__(256) void k1_wh(const float* __restrict__ h,
                                             const _Float16* __restrict__ Wt,
                                             float* __restrict__ Wh) {
  const int r0 = blockIdx.x * 64;
  const int t = threadIdx.x;
  const int w = t >> 6, l = t & 63;
  const int lr = l & 15, lq = l >> 4;
  f32x4 acc[4][4];
#pragma unroll
  for (int m = 0; m < 4; ++m)
#pragma unroll
    for (int n = 0; n < 4; ++n)
#pragma unroll
      for (int q = 0; q < 4; ++q) acc[m][n][q] = 0.f;

  for (int kk = 0; kk < FIN; kk += 32) {
    f16x8 af[4];
#pragma unroll
    for (int m = 0; m < 4; ++m) {
      int gr = r0 + m * 16 + lr;
      if (gr < NN) {
        const f32x4* p = (const f32x4*)(h + (size_t)gr * FIN + kk + lq * 8);
        f32x4 v0 = p[0], v1 = p[1];
#pragma unroll
        for (int i = 0; i < 4; ++i) { af[m][i] = (_Float16)v0[i]; af[m][i + 4] = (_Float16)v1[i]; }
      } else {
#pragma unroll
        for (int i = 0; i < 8; ++i) af[m][i] = (_Float16)0.f;
      }
    }
#pragma unroll
    for (int n = 0; n < 4; ++n) {
      int gc = w * 64 + n * 16 + lr;
      f16x8 bf = *(const f16x8*)(Wt + (size_t)gc * FIN + kk + lq * 8);
#pragma unroll
      for (int m = 0; m < 4; ++m)
        acc[m][n] = __builtin_amdgcn_mfma_f32_16x16x32_f16(af[m], bf, acc[m][n], 0, 0, 0);
    }
  }
#pragma unroll
  for (int m = 0; m < 4; ++m)
#pragma unroll
    for (int n = 0; n < 4; ++n)
#pragma unroll
      for (int q = 0; q < 4; ++q) {
        int gr = r0 + m * 16 + lq * 4 + q;
        if (gr < NN) Wh[(size_t)gr * FOUT + w * 64 + n * 16 + lr] = acc[m][n][q];
      }
}

// ---------------- K2: e1/e2 (padded) + WhT[c][r] bf16 ----------------
__global__ __launch_bounds__(256) void k2_et(const float* __restrict__ Wh,
                                             const float* __restrict__ a,
                                             float* __restrict__ e1,
                                             float* __restrict__ e2,
                                             short* __restrict__ WhT) {
  __shared__ float tile[64][65];
  const int r0 = blockIdx.x * 64;
  const int t = threadIdx.x;
  {
    int r = r0 + (t >> 2);
    int sub = t & 3;
    float s1 = 0.f, s2 = 0.f;
    if (r < NN) {
      for (int i = 0; i < 64; ++i) {
        int c = sub + 4 * i;
        float v = Wh[(size_t)r * FOUT + c];
        s1 += v * a[c];
        s2 += v * a[FOUT + c];
      }
    }
    s1 += __shfl_xor(s1, 1); s1 += __shfl_xor(s1, 2);
    s2 += __shfl_xor(s2, 1); s2 += __shfl_xor(s2, 2);
    if (sub == 0) {
      e1[r] = (r < NN) ? s1 : 0.f;
      e2[r] = (r < NN) ? s2 : 0.f;
    }
  }
  for (int c0 = 0; c0 < FOUT; c0 += 64) {
    __syncthreads();
#pragma unroll
    for (int i = 0; i < 16; ++i) {
      int e = t + 256 * i;
      int row = e >> 6, col = e & 63;
      int grd = r0 + row;
      tile[row][col] = (grd < NN) ? Wh[(size_t)grd * FOUT + c0 + col] : 0.f;
    }
    __syncthreads();
#pragma unroll
    for (int i = 0; i < 16; ++i) {
      int e = t + 256 * i;
      int c = e >> 6, rr = e & 63;
      WhT[(size_t)(c0 + c) * NPAD + r0 + rr] = f2bf(tile[rr][c]);
    }
  }
}

// ---------------- KP: bit-pack adj, vectorized (16 B/lane) ----------------
// One wave per row. Chunk = 256 j. Word (chunk*4+c), bit k  <->  j = chunk*256 + 4k + c.
__global__ __launch_bounds__(256) void kp_bits(const int* __restrict__ adj,
                                               unsigned long long* __restrict__ bits) {
  const int lane = threadIdx.x & 63;
  const int row = (blockIdx.x * 256 + threadIdx.x) >> 6;   // 0..NPAD-1
  unsigned long long* orow = bits + (size_t)row * WPR;
  if (row >= NN) {
    for (int c = lane; c < WPR; c += 64) orow[c] = 0ULL;
    return;
  }
  const int* arow = adj + (size_t)row * NN;
  const int j4 = lane * 4;
  i32x4 cur = *(const i32x4*)(arow + j4);                  // chunk 0 (full)
  for (int c = 0; c < 40; ++c) {
    i32x4 nxt;
    if (c < 38) {
      nxt = *(const i32x4*)(arow + (c + 1) * 256 + j4);
    } else if (c == 38) {                                  // chunk 39 is partial
      int jb = 39 * 256 + j4;
#pragma unroll
      for (int q = 0; q < 4; ++q) nxt[q] = (jb + q < NN) ? arow[jb + q] : 0;
    } else {
      nxt[0] = nxt[1] = nxt[2] = nxt[3] = 0;
    }
    unsigned long long b0 = __ballot(cur[0] > 0);
    unsigned long long b1 = __ballot(cur[1] > 0);
    unsigned long long b2 = __ballot(cur[2] > 0);
    unsigned long long b3 = __ballot(cur[3] > 0);
    if (lane < 4) {
      unsigned long long v = (lane == 0) ? b0 : (lane == 1) ? b1 : (lane == 2) ? b2 : b3;
      orow[c * 4 + lane] = v;
    }
    cur = nxt;
  }
}

// ---------------- K3: partial masked-softmax @ Wh ----------------
// Block = 256 rows x 512-j slice. 1024 thr = 16 waves (4M x 4N; wave = 64r x 64c).
// B (WhT) staged through LDS once per phase (no cross-wave global redundancy),
// async-split: issue B(ph+1) loads -> produce P(ph+1) -> MFMA(ph) -> write B(ph+1).
// One barrier per phase; P and B double-buffered; both read via same XOR swizzle.
#define PRODUCE(PH, BUF)                                                      \
  {                                                                           \
    const int jl_ = (PH) * 64 + sub * 16;                                     \
    f32x4 ea = *(const f32x4*)(e2s + jl_);                                    \
    f32x4 eb = *(const f32x4*)(e2s + jl_ + 4);                                \
    f32x4 ec = *(const f32x4*)(e2s + jl_ + 8);                                \
    f32x4 ed = *(const f32x4*)(e2s + jl_ + 12);                               \
    const unsigned int m16 = mk[(PH) >> 1] >> (((PH) & 1) * 16);              \
    bf16x8 pf0, pf1;                                                          \
    _Pragma("unroll")                                                         \
    for (int i = 0; i < 16; ++i) {                                            \
      float x = e1v + ((i < 4) ? ea[i & 3] : (i < 8) ? eb[i & 3]              \
                       : (i < 12) ? ec[i & 3] : ed[i & 3]);                   \
      float sv = fmaxf(x, LRA * x);                                           \
      float p = ((m16 >> (((i & 3) * 4) + (i >> 2))) & 1) ? __expf(sv) : 0.f; \
      rs += p;                                                                \
      if (i < 8) pf0[i] = f2bf(p); else pf1[i & 7] = f2bf(p);                 \
    }                                                                         \
    char* wb_ = (BUF) + prow * 128;                                           \
    *(bf16x8*)(wb_ + ((sub * 32) ^ psw)) = pf0;                               \
    *(bf16x8*)(wb_ + ((sub * 32 + 16) ^ psw)) = pf1;                          \
  }

#define BISSUE(PH)                                                            \
  brg0 = *(const bf16x8*)(wsrc0 + (PH) * 64);                                 \
  brg1 = *(const bf16x8*)(wsrc1 + (PH) * 64);

#define BWRITE(BUF)                                                           \
  *(bf16x8*)((BUF) + bwoff) = brg0;                                           \
  *(bf16x8*)((BUF) + bwoff + 16384) = brg1;

#define CONSUME(PH, PBUF, BBUF)                                               \
  {                                                                           \
    __builtin_amdgcn_s_setprio(1);                                            \
    _Pragma("unroll")                                                         \
    for (int kt = 0; kt < 2; ++kt) {                                          \
      const int bo_ = (kt * 64 + lq * 16) ^ axor;                             \
      _Pragma("unroll")                                                       \
      for (int mg = 0; mg < 2; ++mg) {                                        \
        bf16x8 av0 = *(const bf16x8*)((PBUF) + (wm * 64 + mg * 32 + lr) * 128 + bo_);      \
        bf16x8 av1 = *(const bf16x8*)((PBUF) + (wm * 64 + mg * 32 + 16 + lr) * 128 + bo_); \
        _Pragma("unroll")                                                     \
        for (int n = 0; n < 4; ++n) {                                         \
          bf16x8 bv = *(const bf16x8*)((BBUF) + (wn * 64 + n * 16 + lr) * 128 + bo_);      \
          acc[mg * 2][n]     = __builtin_amdgcn_mfma_f32_16x16x32_bf16(av0, bv, acc[mg * 2][n], 0, 0, 0);     \
          acc[mg * 2 + 1][n] = __builtin_amdgcn_mfma_f32_16x16x32_bf16(av1, bv, acc[mg * 2 + 1][n], 0, 0, 0); \
        }                                                                     \
      }                                                                       \
    }                                                                         \
    __builtin_amdgcn_s_setprio(0);                                            \
  }

__global__ __launch_bounds__(1024) void k3_part(const unsigned long long* __restrict__ bits,
                                                const float* __restrict__ e1,
                                                const float* __restrict__ e2,
                                                const short* __restrict__ WhT,
                                                short* __restrict__ pnum,
                                                float* __restrict__ pden) {
  __shared__ __align__(16) char Plds[2][32768];   // [256 r][64 j] bf16, XOR-swizzled
  __shared__ __align__(16) char Blds[2][32768];   // [256 c][64 j] bf16, XOR-swizzled
  __shared__ float e2s[JLEN];
  const int id = blockIdx.x;
  const int s = id % NSL;
  const int r0 = (id / NSL) * 256;
  const int jbase = s * JLEN;
  const int t = threadIdx.x;
  const int w = t >> 6, l = t & 63;
  const int lr = l & 15, lq = l >> 4;
  const int wm = w >> 2, wn = w & 3;
  const int prow = t >> 2, sub = t & 3;           // P producer: 4 thr/row, 16 j each
  const int psw = (prow & 7) << 4;
  const int axor = (lr & 7) << 4;
  const int grow = r0 + prow;
  const float e1v = e1[grow];
  // B staging map: thread -> (col sc & sc+128, 8-j segment sseg)
  const int sc = t >> 3, sseg = t & 7;
  const short* wsrc0 = WhT + (size_t)sc * NPAD + jbase + sseg * 8;
  const short* wsrc1 = wsrc0 + (size_t)128 * NPAD;
  const int bwoff = sc * 128 + ((sseg * 16) ^ ((sc & 7) << 4));
  bf16x8 brg0, brg1;

  if (t < JLEN / 4) ((f32x4*)e2s)[t] = ((const f32x4*)(e2 + jbase))[t];

  // per-phase 16-bit masks from packed adjacency (layout verified in R5)
  unsigned int mk[NPH / 2];
  {
    const unsigned long long* wr = bits + (size_t)grow * WPR + (jbase >> 6);
    u64x2 wv0 = *(const u64x2*)(wr + 0);
    u64x2 wv1 = *(const u64x2*)(wr + 2);
    u64x2 wv2 = *(const u64x2*)(wr + 4);
    u64x2 wv3 = *(const u64x2*)(wr + 6);
    unsigned long long wd[8];
    wd[0] = wv0[0]; wd[1] = wv0[1]; wd[2] = wv1[0]; wd[3] = wv1[1];
    wd[4] = wv2[0]; wd[5] = wv2[1]; wd[6] = wv3[0]; wd[7] = wv3[1];
#pragma unroll
    for (int ph = 0; ph < NPH; ++ph) {
      const int base = (ph & 3) * 16 + sub * 4;
      const unsigned long long* wc = wd + (ph >> 2) * 4;
      unsigned int m16 = (unsigned int)((wc[0] >> base) & 0xFULL)
                       | ((unsigned int)((wc[1] >> base) & 0xFULL) << 4)
                       | ((unsigned int)((wc[2] >> base) & 0xFULL) << 8)
                       | ((unsigned int)((wc[3] >> base) & 0xFULL) << 12);
      if (ph & 1) mk[ph >> 1] |= m16 << 16; else mk[ph >> 1] = m16;
    }
  }

  f32x4 acc[4][4];
#pragma unroll
  for (int m = 0; m < 4; ++m)
#pragma unroll
    for (int n = 0; n < 4; ++n)
#pragma unroll
      for (int q = 0; q < 4; ++q) acc[m][n][q] = 0.f;
  float rs = 0.f;

  BISSUE(0);
  __syncthreads();                    // e2s ready
  PRODUCE(0, &Plds[0][0]);
  BWRITE(&Blds[0][0]);                // waits vmcnt for brg

#pragma unroll
  for (int ph = 0; ph < NPH; ++ph) {
    __syncthreads();                  // buf[ph&1] ready; readers of buf[(ph+1)&1] done
    if (ph + 1 < NPH) {
      BISSUE(ph + 1);                 // global loads in flight across the MFMAs
      PRODUCE(ph + 1, &Plds[(ph + 1) & 1][0]);
    }
    CONSUME(ph, &Plds[ph & 1][0], &Blds[ph & 1][0]);
    if (ph + 1 < NPH) BWRITE(&Blds[(ph + 1) & 1][0]);
  }

  rs += __shfl_xor(rs, 1); rs += __shfl_xor(rs, 2);
  if (sub == 0) pden[(size_t)s * NPAD + grow] = rs;
#pragma unroll
  for (int m = 0; m < 4; ++m)
#pragma unroll
    for (int n = 0; n < 4; ++n)
#pragma unroll
      for (int q = 0; q < 4; ++q) {
        int row = wm * 64 + m * 16 + lq * 4 + q;
        pnum[((size_t)s * NPAD + r0 + row) * FOUT + wn * 64 + n * 16 + lr] =
            f2bf(acc[m][n][q]);
      }
}

// ---------------- K4: reduce slices, normalize, elu ----------------
__global__ __launch_bounds__(256) void k4_out(const short* __restrict__ pnum,
                                              const float* __restrict__ pden,
                                              float* __restrict__ out) {
  const int row = blockIdx.x;
  const int c = threadIdx.x;
  float den = 0.f;
#pragma unroll
  for (int s = 0; s < NSL; ++s) den += pden[(size_t)s * NPAD + row];
  float num = 0.f;
#pragma unroll
  for (int s = 0; s < NSL; ++s) num += bf2f(pnum[((size_t)s * NPAD + row) * FOUT + c]);
  float v = num / den;
  out[(size_t)row * FOUT + c] = (v > 0.f) ? v : (__expf(v) - 1.f);
}

// ---------------- Fallback (ws too small): R2 fused k3 ----------------
#define OLD_LOAD(J0N, AV, EV)                                               \
  {                                                                         \
    const int jn_ = (J0N) + jb;                                             \
    EV[0] = *(const f32x4*)(e2 + jn_);                                      \
    EV[1] = *(const f32x4*)(e2 + jn_ + 4);                                  \
    EV[2] = *(const f32x4*)(e2 + jn_ + 128);                                \
    EV[3] = *(const f32x4*)(e2 + jn_ + 132);                                \
    if (rowok && (J0N) + 256 <= NN) {                                       \
      AV[0] = *(const i32x4*)(adj + adjrow + jn_);                          \
      AV[1] = *(const i32x4*)(adj + adjrow + jn_ + 4);                      \
      AV[2] = *(const i32x4*)(adj + adjrow + jn_ + 128);                    \
      AV[3] = *(const i32x4*)(adj + adjrow + jn_ + 132);                    \
    } else {                                                                \
      _Pragma("unroll")                                                     \
      for (int p_ = 0; p_ < 4; ++p_) {                                      \
        _Pragma("unroll")                                                   \
        for (int i_ = 0; i_ < 4; ++i_) {                                    \
          int j_ = jn_ + (p_ >> 1) * 128 + (p_ & 1) * 4 + i_;               \
          AV[p_][i_] = (rowok && j_ < NN) ? adj[adjrow + j_] : 0;           \
        }                                                                   \
      }                                                                     \
    }                                                                       \
  }

#define OLD_PHASE(J0, AV, EV, BUF)                                          \
  {                                                                         \
    bf16x8 pf0, pf1;                                                        \
    _Pragma("unroll")                                                       \
    for (int i = 0; i < 8; ++i) {                                           \
      float x = e1v + EV[i >> 2][i & 3];                                    \
      float s = fmaxf(x, LRA * x);                                          \
      float p = (AV[i >> 2][i & 3] > 0) ? __expf(s) : 0.f;                  \
      rs += p; pf0[i] = f2bf(p);                                            \
    }                                                                       \
    _Pragma("unroll")                                                       \
    for (int i = 0; i < 8; ++i) {                                           \
      float x = e1v + EV[2 + (i >> 2)][i & 3];                              \
      float s = fmaxf(x, LRA * x);                                          \
      float p = (AV[2 + (i >> 2)][i & 3] > 0) ? __expf(s) : 0.f;            \
      rs += p; pf1[i] = f2bf(p);                                            \
    }                                                                       \
    {                                                                       \
      char* wb_ = (BUF) + prow * 512;                                       \
      const int sw_ = (prow & 7) << 4;                                      \
      *(bf16x8*)(wb_ + ((psub * 16) ^ sw_)) = pf0;                          \
      *(bf16x8*)(wb_ + ((256 + psub * 16) ^ sw_)) = pf1;                    \
    }                                                                       \
    __syncthreads();                                                        \
    _Pragma("unroll")                                                       \
    for (int kt = 0; kt < 8; ++kt) {                                        \
      const int boff_ = (kt * 64 + lq * 16) ^ ((lr & 7) << 4);              \
      bf16x8 a0 = *(const bf16x8*)((BUF) + lr * 512 + boff_);               \
      bf16x8 a1 = *(const bf16x8*)((BUF) + (16 + lr) * 512 + boff_);        \
      const short* bp_ = WhT + (J0) + kt * 32 + lq * 8;                     \
      bf16x8 b0 = *(const bf16x8*)(bp_ + bcol0);                            \
      bf16x8 b1 = *(const bf16x8*)(bp_ + bcol1);                            \
      acc[0][0] = __builtin_amdgcn_mfma_f32_16x16x32_bf16(a0, b0, acc[0][0], 0, 0, 0); \
      acc[1][0] = __builtin_amdgcn_mfma_f32_16x16x32_bf16(a1, b0, acc[1][0], 0, 0, 0); \
      acc[0][1] = __builtin_amdgcn_mfma_f32_16x16x32_bf16(a0, b1, acc[0][1], 0, 0, 0); \
      acc[1][1] = __builtin_amdgcn_mfma_f32_16x16x32_bf16(a1, b1, acc[1][1], 0, 0, 0); \
    }                                                                       \
  }

__global__ __launch_bounds__(512) void k3_old(const int* __restrict__ adj,
                                              const float* __restrict__ e1,
                                              const float* __restrict__ e2,
                                              const short* __restrict__ WhT,
                                              float* __restrict__ out) {
  __shared__ __align__(16) char Plds[2][32 * 512];
  __shared__ float rowsum[32];
  const int r0 = blockIdx.x * 32;
  const int t = threadIdx.x;
  const int w = t >> 6, l = t & 63;
  const int lr = l & 15, lq = l >> 4;
  const int prow = t >> 4;
  const int psub = t & 15;
  const int jb = psub * 8;
  const int gr = r0 + prow;
  const bool rowok = (gr < NN);
  const float e1v = rowok ? e1[gr] : 0.f;
  const size_t adjrow = (size_t)gr * NN;
  const size_t bcol0 = (size_t)(w * 32 + lr) * NPAD;
  const size_t bcol1 = (size_t)(w * 32 + 16 + lr) * NPAD;
  float rs = 0.f;
  f32x4 acc[2][2];
#pragma unroll
  for (int m = 0; m < 2; ++m)
#pragma unroll
    for (int n = 0; n < 2; ++n)
#pragma unroll
      for (int q = 0; q < 4; ++q) acc[m][n][q] = 0.f;

  const int NT = (NN + 255) / 256;
  i32x4 avA[4], avB[4];
  f32x4 evA[4], evB[4];
  OLD_LOAD(0, avA, evA);
  for (int jt = 0; jt < NT; jt += 2) {
    OLD_LOAD((jt + 1) * 256, avB, evB);
    OLD_PHASE(jt * 256, avA, evA, &Plds[0][0]);
    if (jt + 2 < NT) OLD_LOAD((jt + 2) * 256, avA, evA);
    OLD_PHASE((jt + 1) * 256, avB, evB, &Plds[1][0]);
  }
  rs += __shfl_xor(rs, 1); rs += __shfl_xor(rs, 2);
  rs += __shfl_xor(rs, 4); rs += __shfl_xor(rs, 8);
  if (psub == 0) rowsum[prow] = rs;
  __syncthreads();
#pragma unroll
  for (int m = 0; m < 2; ++m)
#pragma unroll
    for (int n = 0; n < 2; ++n)
#pragma unroll
      for (int q = 0; q < 4; ++q) {
        int row = m * 16 + lq * 4 + q;
        int grow = r0 + row;
        if (grow < NN) {
          float v = acc[m][n][q] / rowsum[row];
          float o = (v > 0.f) ? v : (__expf(v) - 1.f);
          out[(size_t)grow * FOUT + w * 32 + n * 16 + lr] = o;
        }
      }
}

extern "C" void kernel_launch(void* const* d_in, const int* in_sizes, int n_in,
                              void* d_out, int out_size, void* d_ws, size_t ws_size,
                              hipStream_t stream) {
  const float* h   = (const float*)d_in[0];
  const int*   adj = (const int*)d_in[1];
  const float* W   = (const float*)d_in[2];
  const float* a   = (const float*)d_in[3];
  float* out = (float*)d_out;
  char* ws = (char*)d_ws;
  _Float16* Wt  = (_Float16*)(ws + 0);            // 262144
  float*    Wh  = (float*)(ws + 262144);          // -> 10502144
  short*    WhT = (short*)(ws + 10502144);        // -> 15745024
  float*    e1  = (float*)(ws + 15745024);        // -> 15785984
  float*    e2  = (float*)(ws + 15785984);        // -> 15826944
  unsigned long long* bits = (unsigned long long*)(ws + 15826944);  // 13107200 -> 28934144
  float*    pden = (float*)(ws + 28934144);       // 20*10240*4 = 819200 -> 29753344
  short*    pnum = (short*)(ws + 29753344);       // 20*10240*256*2 = 104857600 -> 134610944
  (void)in_sizes; (void)n_in; (void)out_size;

  const bool big = ws_size >= (size_t)134610944;

  k0_wt<<<dim3(512), dim3(256), 0, stream>>>(W, Wt);
  k1_wh<<<dim3(157), dim3(256), 0, stream>>>(h, Wt, Wh);
  k2_et<<<dim3(160), dim3(256), 0, stream>>>(Wh, a, e1, e2, WhT);

  if (big) {
    kp_bits<<<dim3(NPAD / 4), dim3(256), 0, stream>>>(adj, bits);
    k3_part<<<dim3((NPAD / 256) * NSL), dim3(1024), 0, stream>>>(
        bits, e1, e2, WhT, pnum, pden);
    k4_out<<<dim3(NN), dim3(256), 0, stream>>>(pnum, pden, out);
  } else {
    k3_old<<<dim3(313), dim3(512), 0, stream>>>(adj, e1, e2, WhT, out);
  }
}

// Round 7
// 279.588 us; speedup vs baseline: 1.7251x; 1.1260x over previous
//
#include <hip/hip_runtime.h>
#include <hip/hip_bf16.h>
#include <hip/hip_fp16.h>

#define NN    10000
#define FIN   512
#define FOUT  256
#define NPAD  10240
#define LRA   0.2f
#define NSL   16          // slices (power of 2: slice = id%16 -> 2 slices/XCD, L2-resident B)
#define JLEN  640         // NPAD / NSL
#define NPH   10          // JLEN / 64

typedef __attribute__((ext_vector_type(4))) float    f32x4;
typedef __attribute__((ext_vector_type(4))) int      i32x4;
typedef __attribute__((ext_vector_type(8))) _Float16 f16x8;
typedef __attribute__((ext_vector_type(8))) short    bf16x8;

static __device__ __forceinline__ short f2bf(float x) {
  unsigned u = __builtin_bit_cast(unsigned, x);
  u += 0x7fffu + ((u >> 16) & 1u);   // RNE; x always finite here
  return (short)(u >> 16);
}
static __device__ __forceinline__ float bf2f(short s) {
  unsigned u = ((unsigned)(unsigned short)s) << 16;
  return __builtin_bit_cast(float, u);
}
// async global->LDS, 16B per lane; LDS dest = wave-uniform base + lane*16
static __device__ __forceinline__ void gl16(const short* g, char* l) {
  __builtin_amdgcn_global_load_lds(
      (const __attribute__((address_space(1))) unsigned int*)g,
      (__attribute__((address_space(3))) unsigned int*)l,
      16, 0, 0);
}

// ---------------- K0: Wt[c][k] = f16(W[k][c]) ----------------
__global__ __launch_bounds__(256) void k0_wt(const float* __restrict__ W,
                                             _Float16* __restrict__ Wt) {
  int idx = blockIdx.x * 256 + threadIdx.x;
  int k = idx >> 8, c = idx & 255;
  Wt[(size_t)c * FIN + k] = (_Float16)W[(size_t)k * FOUT + c];
}

// ---------------- K1: Wh = h @ W (f16 MFMA, fp32 accum) ----------------
__global__ __launch_bounds__(256) void k1_wh(const float* __restrict__ h,
                                             const _Float16* __restrict__ Wt,
                                             float* __restrict__ Wh) {
  const int r0 = blockIdx.x * 64;
  const int t = threadIdx.x;
  const int w = t >> 6, l = t & 63;
  const int lr = l & 15, lq = l >> 4;
  f32x4 acc[4][4];
#pragma unroll
  for (int m = 0; m < 4; ++m)
#pragma unroll
    for (int n = 0; n < 4; ++n)
#pragma unroll
      for (int q = 0; q < 4; ++q) acc[m][n][q] = 0.f;

  for (int kk = 0; kk < FIN; kk += 32) {
    f16x8 af[4];
#pragma unroll
    for (int m = 0; m < 4; ++m) {
      int gr = r0 + m * 16 + lr;
      if (gr < NN) {
        const f32x4* p = (const f32x4*)(h + (size_t)gr * FIN + kk + lq * 8);
        f32x4 v0 = p[0], v1 = p[1];
#pragma unroll
        for (int i = 0; i < 4; ++i) { af[m][i] = (_Float16)v0[i]; af[m][i + 4] = (_Float16)v1[i]; }
      } else {
#pragma unroll
        for (int i = 0; i < 8; ++i) af[m][i] = (_Float16)0.f;
      }
    }
#pragma unroll
    for (int n = 0; n < 4; ++n) {
      int gc = w * 64 + n * 16 + lr;
      f16x8 bf = *(const f16x8*)(Wt + (size_t)gc * FIN + kk + lq * 8);
#pragma unroll
      for (int m = 0; m < 4; ++m)
        acc[m][n] = __builtin_amdgcn_mfma_f32_16x16x32_f16(af[m], bf, acc[m][n], 0, 0, 0);
    }
  }
#pragma unroll
  for (int m = 0; m < 4; ++m)
#pragma unroll
    for (int n = 0; n < 4; ++n)
#pragma unroll
      for (int q = 0; q < 4; ++q) {
        int gr = r0 + m * 16 + lq * 4 + q;
        if (gr < NN) Wh[(size_t)gr * FOUT + w * 64 + n * 16 + lr] = acc[m][n][q];
      }
}

// ---------------- K2: e1/e2 (padded) + WhT[c][r] bf16 ----------------
__global__ __launch_bounds__(256) void k2_et(const float* __restrict__ Wh,
                                             const float* __restrict__ a,
                                             float* __restrict__ e1,
                                             float* __restrict__ e2,
                                             short* __restrict__ WhT) {
  __shared__ float tile[64][65];
  const int r0 = blockIdx.x * 64;
  const int t = threadIdx.x;
  {
    int r = r0 + (t >> 2);
    int sub = t & 3;
    float s1 = 0.f, s2 = 0.f;
    if (r < NN) {
      for (int i = 0; i < 64; ++i) {
        int c = sub + 4 * i;
        float v = Wh[(size_t)r * FOUT + c];
        s1 += v * a[c];
        s2 += v * a[FOUT + c];
      }
    }
    s1 += __shfl_xor(s1, 1); s1 += __shfl_xor(s1, 2);
    s2 += __shfl_xor(s2, 1); s2 += __shfl_xor(s2, 2);
    if (sub == 0) {
      e1[r] = (r < NN) ? s1 : 0.f;
      e2[r] = (r < NN) ? s2 : 0.f;
    }
  }
  for (int c0 = 0; c0 < FOUT; c0 += 64) {
    __syncthreads();
#pragma unroll
    for (int i = 0; i < 16; ++i) {
      int e = t + 256 * i;
      int row = e >> 6, col = e & 63;
      int grd = r0 + row;
      tile[row][col] = (grd < NN) ? Wh[(size_t)grd * FOUT + c0 + col] : 0.f;
    }
    __syncthreads();
#pragma unroll
    for (int i = 0; i < 16; ++i) {
      int e = t + 256 * i;
      int c = e >> 6, rr = e & 63;
      WhT[(size_t)(c0 + c) * NPAD + r0 + rr] = f2bf(tile[rr][c]);
    }
  }
}

// ---------------- K3: fused partial masked-softmax @ Wh ----------------
// Block = 256 rows x 640-j slice; 1024 thr = 16 waves (4M x 4N; wave = 64r x 64c).
// adj read directly (no bitpack pass), 1-phase-ahead register prefetch.
// B staged via global_load_lds: linear LDS dest + pre-swizzled global source
// (seg ^ (col&7)); reads use the same XOR -> conflict-free. P double-buffered.
#define LOADADJ(PH)                                                           \
  {                                                                           \
    if (rowok) {                                                              \
      if (jfull >= ((PH) + 1) * 64) {                                         \
        _Pragma("unroll")                                                     \
        for (int q_ = 0; q_ < 4; ++q_)                                        \
          adjr[q_] = *(const i32x4*)(arow + (PH) * 64 + q_ * 4);              \
      } else {                                                                \
        _Pragma("unroll")                                                     \
        for (int q_ = 0; q_ < 4; ++q_) {                                      \
          _Pragma("unroll")                                                   \
          for (int i_ = 0; i_ < 4; ++i_) {                                    \
            int j_ = jbase + (PH) * 64 + sub * 16 + q_ * 4 + i_;              \
            adjr[q_][i_] = (j_ < NN) ? arowg[j_] : 0;                         \
          }                                                                   \
        }                                                                     \
      }                                                                       \
    } else {                                                                  \
      _Pragma("unroll")                                                       \
      for (int q_ = 0; q_ < 4; ++q_) {                                        \
        adjr[q_][0] = 0; adjr[q_][1] = 0; adjr[q_][2] = 0; adjr[q_][3] = 0;   \
      }                                                                       \
    }                                                                         \
  }

#define BLOAD(PH, BUF)                                                        \
  {                                                                           \
    gl16(wsrcA + (PH) * 64, (BUF) + bldso);                                   \
    gl16(wsrcB + (PH) * 64, (BUF) + bldso + 1024);                            \
  }

#define PRODUCE(PH, BUF)                                                      \
  {                                                                           \
    const int jl_ = (PH) * 64 + sub * 16;                                     \
    f32x4 ea = *(const f32x4*)(e2s + jl_);                                    \
    f32x4 eb = *(const f32x4*)(e2s + jl_ + 4);                                \
    f32x4 ec = *(const f32x4*)(e2s + jl_ + 8);                                \
    f32x4 ed = *(const f32x4*)(e2s + jl_ + 12);                               \
    bf16x8 pf0, pf1;                                                          \
    _Pragma("unroll")                                                         \
    for (int i = 0; i < 16; ++i) {                                            \
      float x = e1v + ((i < 4) ? ea[i & 3] : (i < 8) ? eb[i & 3]              \
                       : (i < 12) ? ec[i & 3] : ed[i & 3]);                   \
      float sv = fmaxf(x, LRA * x);                                           \
      float p = (adjr[i >> 2][i & 3] > 0) ? __expf(sv) : 0.f;                 \
      rs += p;                                                                \
      if (i < 8) pf0[i] = f2bf(p); else pf1[i & 7] = f2bf(p);                 \
    }                                                                         \
    char* wb_ = (BUF) + prow * 128;                                           \
    *(bf16x8*)(wb_ + ((sub * 32) ^ psw)) = pf0;                               \
    *(bf16x8*)(wb_ + ((sub * 32 + 16) ^ psw)) = pf1;                          \
  }

#define CONSUME(PBUF, BBUF)                                                   \
  {                                                                           \
    __builtin_amdgcn_s_setprio(1);                                            \
    _Pragma("unroll")                                                         \
    for (int kt = 0; kt < 2; ++kt) {                                          \
      const int bo_ = (kt * 64 + lq * 16) ^ axor;                             \
      bf16x8 av0 = *(const bf16x8*)((PBUF) + (wm * 64 + 0 * 16 + lr) * 128 + bo_); \
      bf16x8 av1 = *(const bf16x8*)((PBUF) + (wm * 64 + 1 * 16 + lr) * 128 + bo_); \
      bf16x8 av2 = *(const bf16x8*)((PBUF) + (wm * 64 + 2 * 16 + lr) * 128 + bo_); \
      bf16x8 av3 = *(const bf16x8*)((PBUF) + (wm * 64 + 3 * 16 + lr) * 128 + bo_); \
      _Pragma("unroll")                                                       \
      for (int n = 0; n < 4; ++n) {                                           \
        bf16x8 bv = *(const bf16x8*)((BBUF) + (wn * 64 + n * 16 + lr) * 128 + bo_); \
        acc[0][n] = __builtin_amdgcn_mfma_f32_16x16x32_bf16(av0, bv, acc[0][n], 0, 0, 0); \
        acc[1][n] = __builtin_amdgcn_mfma_f32_16x16x32_bf16(av1, bv, acc[1][n], 0, 0, 0); \
        acc[2][n] = __builtin_amdgcn_mfma_f32_16x16x32_bf16(av2, bv, acc[2][n], 0, 0, 0); \
        acc[3][n] = __builtin_amdgcn_mfma_f32_16x16x32_bf16(av3, bv, acc[3][n], 0, 0, 0); \
      }                                                                       \
    }                                                                         \
    __builtin_amdgcn_s_setprio(0);                                            \
  }

__global__ __launch_bounds__(1024) void k3_part(const int* __restrict__ adj,
                                                const float* __restrict__ e1,
                                                const float* __restrict__ e2,
                                                const short* __restrict__ WhT,
                                                short* __restrict__ pnum,
                                                float* __restrict__ pden) {
  __shared__ __align__(16) char Plds[2][32768];   // [256 r][64 j] bf16, XOR-swizzled
  __shared__ __align__(16) char Blds[2][32768];   // [256 c][64 j] bf16, XOR-swizzled
  __shared__ float e2s[JLEN];
  const int id = blockIdx.x;
  const int s = id & (NSL - 1);                   // slice: id%16 -> 2 slices per XCD
  const int r0 = (id >> 4) * 256;
  const int jbase = s * JLEN;
  const int t = threadIdx.x;
  const int w = t >> 6, l = t & 63;
  const int lr = l & 15, lq = l >> 4;
  const int wm = w >> 2, wn = w & 3;
  const int prow = t >> 2, sub = t & 3;           // P producer: 4 thr/row, 16 j each
  const int psw = (prow & 7) << 4;
  const int axor = (lr & 7) << 4;
  const int grow = r0 + prow;
  const bool rowok = (grow < NN);
  const float e1v = e1[grow];
  const int jfull = NN - jbase;                   // #valid j in this slice from jbase
  const int* arowg = adj + (size_t)grow * NN;
  const int* arow = arowg + jbase + sub * 16;
  // B staging source (pre-swizzled): wave w covers cols w*16 .. w*16+15
  const int colA = w * 16 + (l >> 3);
  const int soff = ((l & 7) ^ (l >> 3)) * 8;
  const short* wsrcA = WhT + (size_t)colA * NPAD + jbase + soff;
  const short* wsrcB = wsrcA + (size_t)8 * NPAD;
  const int bldso = w * 2048;                     // wave-uniform LDS region

  if (t < JLEN / 4) ((f32x4*)e2s)[t] = ((const f32x4*)(e2 + jbase))[t];

  f32x4 acc[4][4];
#pragma unroll
  for (int m = 0; m < 4; ++m)
#pragma unroll
    for (int n = 0; n < 4; ++n)
#pragma unroll
      for (int q = 0; q < 4; ++q) acc[m][n][q] = 0.f;
  float rs = 0.f;
  i32x4 adjr[4];

  BLOAD(0, &Blds[0][0]);
  LOADADJ(0);
  __syncthreads();                 // e2s + B(0) in LDS, adj(0) in regs (vmcnt drain)
  PRODUCE(0, &Plds[0][0]);
  LOADADJ(1);

#pragma unroll 2
  for (int ph = 0; ph < NPH; ++ph) {
    __syncthreads();               // P(ph), B(ph) visible; prior readers of nxt bufs done
    char* pcur = &Plds[ph & 1][0];
    char* bcur = &Blds[ph & 1][0];
    if (ph + 1 < NPH) {
      BLOAD(ph + 1, &Blds[(ph + 1) & 1][0]);   // DMA in flight across CONSUME
      PRODUCE(ph + 1, &Plds[(ph + 1) & 1][0]); // consumes adjr(ph+1)
      if (ph + 2 < NPH) LOADADJ(ph + 2);       // re-issue into the same reg set
    }
    CONSUME(pcur, bcur);
  }

  rs += __shfl_xor(rs, 1); rs += __shfl_xor(rs, 2);
  if (sub == 0) pden[(size_t)s * NPAD + grow] = rs;
  {
    short* po = pnum + ((size_t)s * NPAD + r0) * FOUT;
#pragma unroll
    for (int m = 0; m < 4; ++m)
#pragma unroll
      for (int n = 0; n < 4; ++n)
#pragma unroll
        for (int q = 0; q < 4; ++q) {
          int row = wm * 64 + m * 16 + lq * 4 + q;
          po[(size_t)row * FOUT + wn * 64 + n * 16 + lr] = f2bf(acc[m][n][q]);
        }
  }
}

// ---------------- K4: reduce slices, normalize, elu ----------------
__global__ __launch_bounds__(256) void k4_out(const short* __restrict__ pnum,
                                              const float* __restrict__ pden,
                                              float* __restrict__ out) {
  const int row = blockIdx.x;
  const int c = threadIdx.x;
  float den = 0.f;
#pragma unroll
  for (int s = 0; s < NSL; ++s) den += pden[(size_t)s * NPAD + row];
  float num = 0.f;
#pragma unroll
  for (int s = 0; s < NSL; ++s) num += bf2f(pnum[((size_t)s * NPAD + row) * FOUT + c]);
  float v = num / den;
  out[(size_t)row * FOUT + c] = (v > 0.f) ? v : (__expf(v) - 1.f);
}

// ---------------- Fallback (ws too small): R2 fused k3 ----------------
#define OLD_LOAD(J0N, AV, EV)                                               \
  {                                                                         \
    const int jn_ = (J0N) + jb;                                             \
    EV[0] = *(const f32x4*)(e2 + jn_);                                      \
    EV[1] = *(const f32x4*)(e2 + jn_ + 4);                                  \
    EV[2] = *(const f32x4*)(e2 + jn_ + 128);                                \
    EV[3] = *(const f32x4*)(e2 + jn_ + 132);                                \
    if (rowok && (J0N) + 256 <= NN) {                                       \
      AV[0] = *(const i32x4*)(adj + adjrow + jn_);                          \
      AV[1] = *(const i32x4*)(adj + adjrow + jn_ + 4);                      \
      AV[2] = *(const i32x4*)(adj + adjrow + jn_ + 128);                    \
      AV[3] = *(const i32x4*)(adj + adjrow + jn_ + 132);                    \
    } else {                                                                \
      _Pragma("unroll")                                                     \
      for (int p_ = 0; p_ < 4; ++p_) {                                      \
        _Pragma("unroll")                                                   \
        for (int i_ = 0; i_ < 4; ++i_) {                                    \
          int j_ = jn_ + (p_ >> 1) * 128 + (p_ & 1) * 4 + i_;               \
          AV[p_][i_] = (rowok && j_ < NN) ? adj[adjrow + j_] : 0;           \
        }                                                                   \
      }                                                                     \
    }                                                                       \
  }

#define OLD_PHASE(J0, AV, EV, BUF)                                          \
  {                                                                         \
    bf16x8 pf0, pf1;                                                        \
    _Pragma("unroll")                                                       \
    for (int i = 0; i < 8; ++i) {                                           \
      float x = e1v + EV[i >> 2][i & 3];                                    \
      float s = fmaxf(x, LRA * x);                                          \
      float p = (AV[i >> 2][i & 3] > 0) ? __expf(s) : 0.f;                  \
      rs += p; pf0[i] = f2bf(p);                                            \
    }                                                                       \
    _Pragma("unroll")                                                       \
    for (int i = 0; i < 8; ++i) {                                           \
      float x = e1v + EV[2 + (i >> 2)][i & 3];                              \
      float s = fmaxf(x, LRA * x);                                          \
      float p = (AV[2 + (i >> 2)][i & 3] > 0) ? __expf(s) : 0.f;            \
      rs += p; pf1[i] = f2bf(p);                                            \
    }                                                                       \
    {                                                                       \
      char* wb_ = (BUF) + prow * 512;                                       \
      const int sw_ = (prow & 7) << 4;                                      \
      *(bf16x8*)(wb_ + ((psub * 16) ^ sw_)) = pf0;                          \
      *(bf16x8*)(wb_ + ((256 + psub * 16) ^ sw_)) = pf1;                    \
    }                                                                       \
    __syncthreads();                                                        \
    _Pragma("unroll")                                                       \
    for (int kt = 0; kt < 8; ++kt) {                                        \
      const int boff_ = (kt * 64 + lq * 16) ^ ((lr & 7) << 4);              \
      bf16x8 a0 = *(const bf16x8*)((BUF) + lr * 512 + boff_);               \
      bf16x8 a1 = *(const bf16x8*)((BUF) + (16 + lr) * 512 + boff_);        \
      const short* bp_ = WhT + (J0) + kt * 32 + lq * 8;                     \
      bf16x8 b0 = *(const bf16x8*)(bp_ + bcol0);                            \
      bf16x8 b1 = *(const bf16x8*)(bp_ + bcol1);                            \
      acc[0][0] = __builtin_amdgcn_mfma_f32_16x16x32_bf16(a0, b0, acc[0][0], 0, 0, 0); \
      acc[1][0] = __builtin_amdgcn_mfma_f32_16x16x32_bf16(a1, b0, acc[1][0], 0, 0, 0); \
      acc[0][1] = __builtin_amdgcn_mfma_f32_16x16x32_bf16(a0, b1, acc[0][1], 0, 0, 0); \
      acc[1][1] = __builtin_amdgcn_mfma_f32_16x16x32_bf16(a1, b1, acc[1][1], 0, 0, 0); \
    }                                                                       \
  }

__global__ __launch_bounds__(512) void k3_old(const int* __restrict__ adj,
                                              const float* __restrict__ e1,
                                              const float* __restrict__ e2,
                                              const short* __restrict__ WhT,
                                              float* __restrict__ out) {
  __shared__ __align__(16) char Plds[2][32 * 512];
  __shared__ float rowsum[32];
  const int r0 = blockIdx.x * 32;
  const int t = threadIdx.x;
  const int w = t >> 6, l = t & 63;
  const int lr = l & 15, lq = l >> 4;
  const int prow = t >> 4;
  const int psub = t & 15;
  const int jb = psub * 8;
  const int gr = r0 + prow;
  const bool rowok = (gr < NN);
  const float e1v = rowok ? e1[gr] : 0.f;
  const size_t adjrow = (size_t)gr * NN;
  const size_t bcol0 = (size_t)(w * 32 + lr) * NPAD;
  const size_t bcol1 = (size_t)(w * 32 + 16 + lr) * NPAD;
  float rs = 0.f;
  f32x4 acc[2][2];
#pragma unroll
  for (int m = 0; m < 2; ++m)
#pragma unroll
    for (int n = 0; n < 2; ++n)
#pragma unroll
      for (int q = 0; q < 4; ++q) acc[m][n][q] = 0.f;

  const int NT = (NN + 255) / 256;
  i32x4 avA[4], avB[4];
  f32x4 evA[4], evB[4];
  OLD_LOAD(0, avA, evA);
  for (int jt = 0; jt < NT; jt += 2) {
    OLD_LOAD((jt + 1) * 256, avB, evB);
    OLD_PHASE(jt * 256, avA, evA, &Plds[0][0]);
    if (jt + 2 < NT) OLD_LOAD((jt + 2) * 256, avA, evA);
    OLD_PHASE((jt + 1) * 256, avB, evB, &Plds[1][0]);
  }
  rs += __shfl_xor(rs, 1); rs += __shfl_xor(rs, 2);
  rs += __shfl_xor(rs, 4); rs += __shfl_xor(rs, 8);
  if (psub == 0) rowsum[prow] = rs;
  __syncthreads();
#pragma unroll
  for (int m = 0; m < 2; ++m)
#pragma unroll
    for (int n = 0; n < 2; ++n)
#pragma unroll
      for (int q = 0; q < 4; ++q) {
        int row = m * 16 + lq * 4 + q;
        int grow = r0 + row;
        if (grow < NN) {
          float v = acc[m][n][q] / rowsum[row];
          float o = (v > 0.f) ? v : (__expf(v) - 1.f);
          out[(size_t)grow * FOUT + w * 32 + n * 16 + lr] = o;
        }
      }
}

extern "C" void kernel_launch(void* const* d_in, const int* in_sizes, int n_in,
                              void* d_out, int out_size, void* d_ws, size_t ws_size,
                              hipStream_t stream) {
  const float* h   = (const float*)d_in[0];
  const int*   adj = (const int*)d_in[1];
  const float* W   = (const float*)d_in[2];
  const float* a   = (const float*)d_in[3];
  float* out = (float*)d_out;
  char* ws = (char*)d_ws;
  _Float16* Wt  = (_Float16*)(ws + 0);            // 262144
  float*    Wh  = (float*)(ws + 262144);          // -> 10502144
  short*    WhT = (short*)(ws + 10502144);        // -> 15745024
  float*    e1  = (float*)(ws + 15745024);        // -> 15785984
  float*    e2  = (float*)(ws + 15785984);        // -> 15826944
  float*    pden = (float*)(ws + 15826944);       // 16*10240*4 = 655360 -> 16482304
  short*    pnum = (short*)(ws + 16482304);       // 16*10240*256*2 = 83886080 -> 100368384
  (void)in_sizes; (void)n_in; (void)out_size;

  const bool big = ws_size >= (size_t)100368384;

  k0_wt<<<dim3(512), dim3(256), 0, stream>>>(W, Wt);
  k1_wh<<<dim3(157), dim3(256), 0, stream>>>(h, Wt, Wh);
  k2_et<<<dim3(160), dim3(256), 0, stream>>>(Wh, a, e1, e2, WhT);

  if (big) {
    k3_part<<<dim3((NPAD / 256) * NSL), dim3(1024), 0, stream>>>(
        adj, e1, e2, WhT, pnum, pden);
    k4_out<<<dim3(NN), dim3(256), 0, stream>>>(pnum, pden, out);
  } else {
    k3_old<<<dim3(313), dim3(512), 0, stream>>>(adj, e1, e2, WhT, out);
  }
}